// Round 3
// baseline (326.771 us; speedup 1.0000x reference)
//
#include <hip/hip_runtime.h>
#include <hip/hip_bf16.h>
#include <stdint.h>

typedef __attribute__((ext_vector_type(8))) __bf16 bf16x8;
typedef __attribute__((ext_vector_type(4))) float f32x4;

constexpr int K_DIM = 4096;
constexpr int N_DIM = 11008;
constexpr int M_DIM = 256;   // B*S
constexpr int TM = 256;      // full M per block
constexpr int TN = 128;      // N cols per block
constexpr int BK = 64;       // K per tile
constexpr int NT = 256;      // 4 waves: 2x2 grid, each wave 128M x 64N
constexpr int KT_ALL = K_DIM / BK;   // 64
constexpr int KSPLIT = 6;    // grid = 86*6 = 516 ~ 2 blocks/CU

__device__ __forceinline__ void gload_lds16(const __bf16* gptr, __bf16* lptr) {
  __builtin_amdgcn_global_load_lds(
      (const __attribute__((address_space(1))) uint32_t*)gptr,
      (__attribute__((address_space(3))) uint32_t*)lptr, 16, 0, 0);
}

__device__ __forceinline__ bf16x8 cvt8(const float4 u0, const float4 u1) {
  bf16x8 v;
  v[0] = (__bf16)u0.x; v[1] = (__bf16)u0.y; v[2] = (__bf16)u0.z; v[3] = (__bf16)u0.w;
  v[4] = (__bf16)u1.x; v[5] = (__bf16)u1.y; v[6] = (__bf16)u1.z; v[7] = (__bf16)u1.w;
  return v;
}

// x fp32 [256][4096] -> xws bf16 row-major [256][4096] (coalesced both sides)
__global__ void cvt_x_kernel(const float* __restrict__ x, __bf16* __restrict__ ws) {
  const int i = (blockIdx.x * 256 + threadIdx.x) * 8;
  const float4 u0 = ((const float4*)(x + i))[0];
  const float4 u1 = ((const float4*)(x + i))[1];
  *(bf16x8*)(ws + i) = cvt8(u0, u1);
}

template<bool USE_WS>
__global__ __launch_bounds__(NT, 2) void int8_linear_kernel(
    const float* __restrict__ x,     // [256,4096] fp32 (fallback path)
    const __bf16* __restrict__ xws,  // [256,4096] bf16 row-major (fast path)
    const int*   __restrict__ w,     // [11008,4096] int32 (int8 widened)
    const float* __restrict__ scale, // [11008]
    const float* __restrict__ bias,  // [11008]
    float*       __restrict__ out)   // [256,11008] fp32, pre-zeroed, atomic-accumulated
{
  // A: 256x64 bf16, single-buffered, staged by global_load_lds with the XOR
  //    chunk swizzle applied to the SOURCE address (linear LDS dest, rule #21).
  // W: int32 -> regs -> cvt -> bf16 LDS, double-buffered, swizzled on write.
  // Swizzle slot = chunk ^ (row&7): frag ds_read_b128 lands 2 lanes/bank (free).
  __shared__ __bf16 As[TM * BK];       // 32 KB
  __shared__ __bf16 Wsh[2][TN * BK];   // 2 x 16 KB  -> 64 KB total, 2 blocks/CU

  const int tid  = threadIdx.x;
  const int lane = tid & 63;
  const int wv   = tid >> 6;
  const int quad = lane >> 4;
  const int l16  = lane & 15;
  const int wm   = wv >> 1;            // M half (128 rows)
  const int wn   = wv & 1;             // N half (64 cols)
  const int n_base = blockIdx.x * TN;
  const int kc     = blockIdx.y;

  // split-K tile range over 64 tiles: {10,11,11,10,11,11}
  const int t0 = (kc * KT_ALL) / KSPLIT;
  const int t1 = ((kc + 1) * KT_ALL) / KSPLIT;
  const int ntile = t1 - t0;
  const int k0 = t0 * BK;

  // W staging: thread owns half a row: row = tid>>1, 16B-chunks [wc0, wc0+4)
  const int wrow = tid >> 1;
  const int wc0  = (tid & 1) * 4;
  const int* wptr = w + (int64_t)(n_base + wrow) * K_DIM + k0 + wc0 * 8;

  f32x4 acc[8][4];
#pragma unroll
  for (int i = 0; i < 8; ++i)
#pragma unroll
    for (int j = 0; j < 4; ++j) acc[i][j] = (f32x4){0.f, 0.f, 0.f, 0.f};

  int4 wr[8];  // 32 int32 of W in flight
  auto wload = [&](int t) {
    const int4* p = (const int4*)(wptr + t * BK);
#pragma unroll
    for (int j = 0; j < 8; ++j) wr[j] = p[j];
  };
  auto commitW = [&](__bf16* wbuf) {
#pragma unroll
    for (int j = 0; j < 4; ++j) {
      const int4 a = wr[j * 2], b = wr[j * 2 + 1];
      bf16x8 v;
      v[0] = (__bf16)(float)a.x; v[1] = (__bf16)(float)a.y;
      v[2] = (__bf16)(float)a.z; v[3] = (__bf16)(float)a.w;
      v[4] = (__bf16)(float)b.x; v[5] = (__bf16)(float)b.y;
      v[6] = (__bf16)(float)b.z; v[7] = (__bf16)(float)b.w;
      const int slot = (wc0 + j) ^ (wrow & 7);
      *(bf16x8*)(wbuf + wrow * BK + slot * 8) = v;
    }
  };
  // A tile stage: 2048 16B-chunks; thread handles c = j*256+tid (8 insts).
  // LDS chunk c = (row=c>>3, slot=c&7) holds global chunk k8 = slot^(row&7).
  auto a_stage = [&](int t) {
    if (USE_WS) {
#pragma unroll
      for (int j = 0; j < 8; ++j) {
        const int c = j * 256 + tid;
        const int row = c >> 3;
        const int k8 = (c & 7) ^ (row & 7);
        gload_lds16(xws + (int64_t)row * K_DIM + (t0 + t) * BK + k8 * 8, As + c * 8);
      }
    } else {
#pragma unroll
      for (int j = 0; j < 8; ++j) {
        const int c = j * 256 + tid;
        const int row = c >> 3;
        const int k8 = c & 7;
        const float* s = x + (int64_t)row * K_DIM + (t0 + t) * BK + k8 * 8;
        const bf16x8 v = cvt8(((const float4*)s)[0], ((const float4*)s)[1]);
        const int slot = k8 ^ (row & 7);
        *(bf16x8*)(As + row * BK + slot * 8) = v;
      }
    }
  };
  auto compute = [&](const __bf16* wbuf) {
#pragma unroll
    for (int ks = 0; ks < 2; ++ks) {
      bf16x8 a[8], b[4];
#pragma unroll
      for (int mi = 0; mi < 8; ++mi) {
        const int m = wm * 128 + mi * 16 + l16;
        const int slot = (ks * 4 + quad) ^ (m & 7);
        a[mi] = *(const bf16x8*)(As + m * BK + slot * 8);
      }
#pragma unroll
      for (int ni = 0; ni < 4; ++ni) {
        const int n = wn * 64 + ni * 16 + l16;
        const int slot = (ks * 4 + quad) ^ (n & 7);
        b[ni] = *(const bf16x8*)(wbuf + n * BK + slot * 8);
      }
#pragma unroll
      for (int mi = 0; mi < 8; ++mi)
#pragma unroll
        for (int ni = 0; ni < 4; ++ni)
          acc[mi][ni] = __builtin_amdgcn_mfma_f32_16x16x32_bf16(
              a[mi], b[ni], acc[mi][ni], 0, 0, 0);
    }
  };

  // Prologue: W(0) committed, A(0) in flight.
  wload(0);
  commitW(Wsh[0]);
  a_stage(0);
  __syncthreads();

  // m97 2-barrier loop. W(t+1) loads issue BEFORE compute(t) (latency hides
  // under 64 MFMAs); A(t+1) gload issues between the barriers (single buffer);
  // the 2nd barrier's vmcnt(0) drain is covered by the co-resident block.
  for (int t = 0; t < ntile; ++t) {
    const bool more = (t + 1 < ntile);
    if (more) wload(t + 1);
    compute(Wsh[t & 1]);
    if (more) {
      commitW(Wsh[(t + 1) & 1]);
      __syncthreads();           // all waves done reading As / Wsh[t&1]
      a_stage(t + 1);
      __syncthreads();           // A landed, W commits visible
    }
  }

  // Epilogue: C/D layout col=lane&15, row=quad*4+reg (m89-verified).
  // Scale per-partial (linear); bias added exactly once by the kc==0 block.
#pragma unroll
  for (int ni = 0; ni < 4; ++ni) {
    const int col = n_base + wn * 64 + ni * 16 + l16;
    const float sc = scale[col];
    const float bi = (kc == 0) ? bias[col] : 0.0f;
#pragma unroll
    for (int mi = 0; mi < 8; ++mi) {
      const int row0 = wm * 128 + mi * 16 + quad * 4;
#pragma unroll
      for (int r = 0; r < 4; ++r)
        unsafeAtomicAdd(out + (int64_t)(row0 + r) * N_DIM + col,
                        acc[mi][ni][r] * sc + bi);
    }
  }
}

extern "C" void kernel_launch(void* const* d_in, const int* in_sizes, int n_in,
                              void* d_out, int out_size, void* d_ws, size_t ws_size,
                              hipStream_t stream) {
  const float* x     = (const float*)d_in[0];
  const int*   w     = (const int*)d_in[1];
  const float* scale = (const float*)d_in[2];
  const float* bias  = (const float*)d_in[3];
  float* out = (float*)d_out;

  __bf16* xws = (__bf16*)d_ws;
  const bool use_ws = ws_size >= (size_t)M_DIM * K_DIM * sizeof(__bf16);

  // split-K partials accumulate via atomics -> zero the output first
  hipMemsetAsync(out, 0, (size_t)M_DIM * N_DIM * sizeof(float), stream);

  dim3 grid(N_DIM / TN, KSPLIT), block(NT);
  if (use_ws) {
    cvt_x_kernel<<<M_DIM * K_DIM / (256 * 8), 256, 0, stream>>>(x, xws);
    int8_linear_kernel<true><<<grid, block, 0, stream>>>(x, xws, w, scale, bias, out);
  } else {
    int8_linear_kernel<false><<<grid, block, 0, stream>>>(x, xws, w, scale, bias, out);
  }
}

// Round 4
// 306.363 us; speedup vs baseline: 1.0666x; 1.0666x over previous
//
#include <hip/hip_runtime.h>
#include <hip/hip_bf16.h>
#include <stdint.h>

typedef __attribute__((ext_vector_type(8))) __bf16 bf16x8;
typedef __attribute__((ext_vector_type(4))) float f32x4;

constexpr int K_DIM = 4096;
constexpr int N_DIM = 11008;
constexpr int M_DIM = 256;   // B*S
constexpr int TM = 256;      // full M per block
constexpr int TN = 64;       // N cols per block
constexpr int BK = 64;       // K per tile
constexpr int NT = 512;      // 8 waves: 4M x 2N, each wave 64M x 32N
constexpr int KT_ALL = K_DIM / BK;   // 64
constexpr int KSPLIT = 3;    // grid = 172*3 = 516 ~ 2 blocks/CU

__device__ __forceinline__ void gload_lds16(const __bf16* gptr, __bf16* lptr) {
  __builtin_amdgcn_global_load_lds(
      (const __attribute__((address_space(1))) uint32_t*)gptr,
      (__attribute__((address_space(3))) uint32_t*)lptr, 16, 0, 0);
}

__device__ __forceinline__ bf16x8 cvt8(const float4 u0, const float4 u1) {
  bf16x8 v;
  v[0] = (__bf16)u0.x; v[1] = (__bf16)u0.y; v[2] = (__bf16)u0.z; v[3] = (__bf16)u0.w;
  v[4] = (__bf16)u1.x; v[5] = (__bf16)u1.y; v[6] = (__bf16)u1.z; v[7] = (__bf16)u1.w;
  return v;
}

// x fp32 [256][4096] -> xws bf16 row-major [256][4096] (coalesced both sides)
__global__ void cvt_x_kernel(const float* __restrict__ x, __bf16* __restrict__ ws) {
  const int i = (blockIdx.x * 256 + threadIdx.x) * 8;
  const float4 u0 = ((const float4*)(x + i))[0];
  const float4 u1 = ((const float4*)(x + i))[1];
  *(bf16x8*)(ws + i) = cvt8(u0, u1);
}

template<bool USE_WS>
__global__ __launch_bounds__(NT, 4) void int8_linear_kernel(
    const float* __restrict__ x,     // [256,4096] fp32 (fallback path)
    const __bf16* __restrict__ xws,  // [256,4096] bf16 row-major (fast path)
    const int*   __restrict__ w,     // [11008,4096] int32 (int8 widened)
    const float* __restrict__ scale, // [11008]
    const float* __restrict__ bias,  // [11008]
    float*       __restrict__ out)   // [256,11008] fp32, pre-zeroed, atomic-accumulated
{
  // Counted-vmcnt pipeline (T3/T4): raw s_barrier per phase, NEVER vmcnt(0)
  // in steady state. W regs 2 tiles ahead; A via gload_lds 1 tile ahead.
  // Per-phase ledger (per wave, steady state), oldest->newest:
  //   entry: [W(t+1):2]
  //   +A(t+1):4 (gload_lds)  +W(t+2):2
  //   commitW(t+1): compiler-counted wait retires W(t+1) only
  //   compute(t)
  //   s_waitcnt vmcnt(2): retires A(t+1), KEEPS W(t+2) in flight across barrier
  //   lgkmcnt(0); s_barrier
  __shared__ __bf16 As[2][TM * BK];    // 2 x 32 KB
  __shared__ __bf16 Wsh[2][TN * BK];   // 2 x 8 KB   -> 80 KB total, 2 blocks/CU

  const int tid  = threadIdx.x;
  const int lane = tid & 63;
  const int wv   = tid >> 6;
  const int quad = lane >> 4;
  const int l16  = lane & 15;
  const int wm   = wv >> 1;            // 0..3 -> 64-row group
  const int wn   = wv & 1;             // 0..1 -> 32-col group
  const int m_base = wm * 64;
  const int n_base = blockIdx.x * TN;
  const int kc     = blockIdx.y;

  // split-K tile range over 64 tiles: {21,21,22}
  const int t0 = (kc * KT_ALL) / KSPLIT;
  const int t1 = ((kc + 1) * KT_ALL) / KSPLIT;
  const int ntile = t1 - t0;
  const int k0 = t0 * BK;

  // W staging: thread owns 8 int32 (chunk wchunk) of row wrow
  const int wrow   = tid >> 3;         // 0..63
  const int wchunk = tid & 7;
  const int wslot  = wchunk ^ (wrow & 7);
  const int* wptr = w + (int64_t)(n_base + wrow) * K_DIM + k0 + wchunk * 8;

  f32x4 acc[4][2];
#pragma unroll
  for (int i = 0; i < 4; ++i)
#pragma unroll
    for (int j = 0; j < 2; ++j) acc[i][j] = (f32x4){0.f, 0.f, 0.f, 0.f};

  int4 wrA[2], wrB[2];   // two W tiles in flight (named, static-indexed)
  auto wload = [&](int t, int4* wr) {
    const int4* p = (const int4*)(wptr + t * BK);
    wr[0] = p[0]; wr[1] = p[1];
  };
  auto commitW = [&](const int4* wr, __bf16* wbuf) {
    bf16x8 v;
    v[0] = (__bf16)(float)wr[0].x; v[1] = (__bf16)(float)wr[0].y;
    v[2] = (__bf16)(float)wr[0].z; v[3] = (__bf16)(float)wr[0].w;
    v[4] = (__bf16)(float)wr[1].x; v[5] = (__bf16)(float)wr[1].y;
    v[6] = (__bf16)(float)wr[1].z; v[7] = (__bf16)(float)wr[1].w;
    *(bf16x8*)(wbuf + wrow * BK + wslot * 8) = v;
  };
  // A tile: 2048 16B-chunks over 512 threads -> 4 gload_lds each.
  // LDS chunk c=(row=c>>3, slot=c&7) holds global chunk k8 = slot^(row&7).
  auto a_stage = [&](int t, __bf16* abuf) {
    if (USE_WS) {
#pragma unroll
      for (int j = 0; j < 4; ++j) {
        const int c = j * 512 + tid;
        const int row = c >> 3;
        const int k8 = (c & 7) ^ (row & 7);
        gload_lds16(xws + (int64_t)row * K_DIM + (t0 + t) * BK + k8 * 8, abuf + c * 8);
      }
    } else {
#pragma unroll
      for (int j = 0; j < 4; ++j) {
        const int c = j * 512 + tid;
        const int row = c >> 3;
        const int k8 = c & 7;
        const float* s = x + (int64_t)row * K_DIM + (t0 + t) * BK + k8 * 8;
        const bf16x8 v = cvt8(((const float4*)s)[0], ((const float4*)s)[1]);
        const int slot = k8 ^ (row & 7);
        *(bf16x8*)(abuf + row * BK + slot * 8) = v;
      }
    }
  };
  auto compute = [&](const __bf16* abuf, const __bf16* wbuf) {
#pragma unroll
    for (int ks = 0; ks < 2; ++ks) {
      bf16x8 a[4], b[2];
#pragma unroll
      for (int mi = 0; mi < 4; ++mi) {
        const int m = m_base + mi * 16 + l16;
        const int slot = (ks * 4 + quad) ^ (m & 7);
        a[mi] = *(const bf16x8*)(abuf + m * BK + slot * 8);
      }
#pragma unroll
      for (int ni = 0; ni < 2; ++ni) {
        const int n = wn * 32 + ni * 16 + l16;
        const int slot = (ks * 4 + quad) ^ (n & 7);
        b[ni] = *(const bf16x8*)(wbuf + n * BK + slot * 8);
      }
#pragma unroll
      for (int mi = 0; mi < 4; ++mi)
#pragma unroll
        for (int ni = 0; ni < 2; ++ni)
          acc[mi][ni] = __builtin_amdgcn_mfma_f32_16x16x32_bf16(
              a[mi], b[ni], acc[mi][ni], 0, 0, 0);
    }
  };

  // Prologue. Ledger: [W0:2][A0:4][W1:2]; commitW waits W0 (compiler-counted);
  // vmcnt(2) retires A0, keeps W1 in flight across the barrier.
  wload(0, wrA);
  __builtin_amdgcn_sched_barrier(0);
  a_stage(0, As[0]);
  __builtin_amdgcn_sched_barrier(0);
  wload(1, wrB);
  commitW(wrA, Wsh[0]);
  asm volatile("s_waitcnt vmcnt(2)" ::: "memory");
  asm volatile("s_waitcnt lgkmcnt(0)" ::: "memory");
  __builtin_amdgcn_sched_barrier(0);
  __builtin_amdgcn_s_barrier();
  __builtin_amdgcn_sched_barrier(0);

  for (int t = 0; t < ntile; t += 2) {
    {  // even phase: tile t from As[0]/Wsh[0]; wrB holds W(t+1)
      const bool hA = (t + 1 < ntile);
      const bool hW = (t + 2 < ntile);
      if (hA) a_stage(t + 1, As[1]);
      __builtin_amdgcn_sched_barrier(0);
      if (hW) wload(t + 2, wrA);
      if (hA) commitW(wrB, Wsh[1]);
      compute(As[0], Wsh[0]);
      if (hA) {
        if (hW) asm volatile("s_waitcnt vmcnt(2)" ::: "memory");
        else    asm volatile("s_waitcnt vmcnt(0)" ::: "memory");
        asm volatile("s_waitcnt lgkmcnt(0)" ::: "memory");
        __builtin_amdgcn_sched_barrier(0);
        __builtin_amdgcn_s_barrier();
        __builtin_amdgcn_sched_barrier(0);
      }
    }
    if (t + 1 < ntile) {  // odd phase: tile t+1 from As[1]/Wsh[1]; wrA holds W(t+2)
      const bool hA = (t + 2 < ntile);
      const bool hW = (t + 3 < ntile);
      if (hA) a_stage(t + 2, As[0]);
      __builtin_amdgcn_sched_barrier(0);
      if (hW) wload(t + 3, wrB);
      if (hA) commitW(wrA, Wsh[0]);
      compute(As[1], Wsh[1]);
      if (hA) {
        if (hW) asm volatile("s_waitcnt vmcnt(2)" ::: "memory");
        else    asm volatile("s_waitcnt vmcnt(0)" ::: "memory");
        asm volatile("s_waitcnt lgkmcnt(0)" ::: "memory");
        __builtin_amdgcn_sched_barrier(0);
        __builtin_amdgcn_s_barrier();
        __builtin_amdgcn_sched_barrier(0);
      }
    }
  }

  // Epilogue: C/D layout col=lane&15, row=quad*4+reg (m89-verified).
  // Scale per-partial (linear); bias added exactly once by the kc==0 block.
#pragma unroll
  for (int ni = 0; ni < 2; ++ni) {
    const int col = n_base + wn * 32 + ni * 16 + l16;
    const float sc = scale[col];
    const float bi = (kc == 0) ? bias[col] : 0.0f;
#pragma unroll
    for (int mi = 0; mi < 4; ++mi) {
      const int row0 = m_base + mi * 16 + quad * 4;
#pragma unroll
      for (int r = 0; r < 4; ++r)
        unsafeAtomicAdd(out + (int64_t)(row0 + r) * N_DIM + col,
                        acc[mi][ni][r] * sc + bi);
    }
  }
}

extern "C" void kernel_launch(void* const* d_in, const int* in_sizes, int n_in,
                              void* d_out, int out_size, void* d_ws, size_t ws_size,
                              hipStream_t stream) {
  const float* x     = (const float*)d_in[0];
  const int*   w     = (const int*)d_in[1];
  const float* scale = (const float*)d_in[2];
  const float* bias  = (const float*)d_in[3];
  float* out = (float*)d_out;

  __bf16* xws = (__bf16*)d_ws;
  const bool use_ws = ws_size >= (size_t)M_DIM * K_DIM * sizeof(__bf16);

  // split-K partials accumulate via atomics -> zero the output first
  hipMemsetAsync(out, 0, (size_t)M_DIM * N_DIM * sizeof(float), stream);

  dim3 grid(N_DIM / TN, KSPLIT), block(NT);
  if (use_ws) {
    cvt_x_kernel<<<M_DIM * K_DIM / (256 * 8), 256, 0, stream>>>(x, xws);
    int8_linear_kernel<true><<<grid, block, 0, stream>>>(x, xws, w, scale, bias, out);
  } else {
    int8_linear_kernel<false><<<grid, block, 0, stream>>>(x, xws, w, scale, bias, out);
  }
}